// Round 9
// baseline (1088.531 us; speedup 1.0000x reference)
//
#include <hip/hip_runtime.h>
#include <stdint.h>
#include <math.h>

#define NE 8
#define NT 8192
#define NH 1024
#define NI 4096
#define BM 128
#define BK 32

typedef _Float16 half8 __attribute__((ext_vector_type(8)));
typedef float f32x4 __attribute__((ext_vector_type(4)));

// ---------------- workspace layout ----------------
// ints at base: [0..8) cnt  [8..17) off  [17..25) cursor  [25..34) mbcum
// int 64..            : te[NT*2]
// int 64+NT*2         : tw[NT*2] (float)
// int 64+NT*4         : tok_slot[NT*2]
// int 64+NT*6         : w_slot[NT*2] (float)
// byte 0.5MiB : x16   (NT*NH f16, 16 MiB)
// byte 18MiB  : act   (NT*2*NI f16, 128 MiB)
// byte 146MiB : gup16 (E*2*NI*NH f16, 128 MiB)
// byte 274MiB : dp16  (E*NH*NI f16, 64 MiB)   -> ends 338 MiB (fits, proven R2-R7)
#define OFF_X16   (512u << 10)
#define OFF_ACT   (18u << 20)
#define OFF_GUP16 (146ull << 20)
#define OFF_DP16  (274ull << 20)

__device__ __forceinline__ half8 pack_half8(float4 a, float4 b) {
  half8 h;
  h[0] = (_Float16)a.x; h[1] = (_Float16)a.y; h[2] = (_Float16)a.z; h[3] = (_Float16)a.w;
  h[4] = (_Float16)b.x; h[5] = (_Float16)b.y; h[6] = (_Float16)b.z; h[7] = (_Float16)b.w;
  return h;
}

__device__ __forceinline__ void gload16(const void* g, void* l) {
  __builtin_amdgcn_global_load_lds(
      (const __attribute__((address_space(1))) uint32_t*)g,
      (__attribute__((address_space(3))) uint32_t*)l, 16, 0, 0);
}

// counted-vmcnt pipeline primitives (T4): raw barrier, NO compiler drain.
// CORRECTNESS RULE (R8 NaN post-mortem): vmcnt is PER-WAVE; a wave's LDS writes
// are only visible-safe to OTHER waves' ds_reads after {this wave's s_waitcnt
// vmcnt} -> {s_barrier} -> {reader}. Every PIPE_WAIT at a tile top MUST be
// followed by PIPE_BAR before any ds_read of staged data.
#define PIPE_WAIT(N) asm volatile("s_waitcnt vmcnt(" #N ")" ::: "memory")
#define PIPE_BAR() do { asm volatile("" ::: "memory"); \
                        __builtin_amdgcn_s_barrier(); \
                        asm volatile("" ::: "memory"); } while (0)
#define LGKM0() do { asm volatile("s_waitcnt lgkmcnt(0)" ::: "memory"); \
                     __builtin_amdgcn_sched_barrier(0); } while (0)
#define MF(a,b,c) __builtin_amdgcn_mfma_f32_16x16x32_f16((a),(b),(c),0,0,0)

// ---------------- weight convert f32 -> f16 ----------------
__global__ __launch_bounds__(256) void convert_w(
    const float* __restrict__ src, _Float16* __restrict__ dst, int n8)
{
  int stride = gridDim.x * 256;
  for (int i = blockIdx.x * 256 + threadIdx.x; i < n8; i += stride) {
    const float4* p = (const float4*)(src + (size_t)i * 8);
    float4 a = p[0], b = p[1];
    *(half8*)(dst + (size_t)i * 8) = pack_half8(a, b);
  }
}

// ---------------- router ----------------
__global__ __launch_bounds__(256) void moe_router(
    const float* __restrict__ x, const float* __restrict__ rw,
    int* __restrict__ iws, _Float16* __restrict__ x16)
{
  int wid  = threadIdx.x >> 6;
  int lane = threadIdx.x & 63;
  int t = (blockIdx.x << 2) + wid;  // one wave per token

  const float4* xp4 = (const float4*)(x + (size_t)t * NH + lane * 16);
  float xv[16];
  #pragma unroll
  for (int j = 0; j < 4; ++j) {
    float4 v = xp4[j];
    xv[4*j+0] = v.x; xv[4*j+1] = v.y; xv[4*j+2] = v.z; xv[4*j+3] = v.w;
  }
  half8 h0, h1;
  #pragma unroll
  for (int j = 0; j < 8; ++j) { h0[j] = (_Float16)xv[j]; h1[j] = (_Float16)xv[8+j]; }
  half8* xo = (half8*)(x16 + (size_t)t * NH + lane * 16);
  xo[0] = h0; xo[1] = h1;

  float lg[NE];
  #pragma unroll
  for (int e = 0; e < NE; ++e) {
    const float4* wp4 = (const float4*)(rw + e * NH + lane * 16);
    float s = 0.f;
    #pragma unroll
    for (int j = 0; j < 4; ++j) {
      float4 w = wp4[j];
      s += xv[4*j+0]*w.x + xv[4*j+1]*w.y + xv[4*j+2]*w.z + xv[4*j+3]*w.w;
    }
    lg[e] = s;
  }
  #pragma unroll
  for (int d = 32; d > 0; d >>= 1) {
    #pragma unroll
    for (int e = 0; e < NE; ++e) lg[e] += __shfl_xor(lg[e], d, 64);
  }
  if (lane == 0) {
    int e0 = 0;
    #pragma unroll
    for (int e = 1; e < NE; ++e) if (lg[e] > lg[e0]) e0 = e;
    int e1 = (e0 == 0) ? 1 : 0;
    #pragma unroll
    for (int e = 0; e < NE; ++e) if (e != e0 && lg[e] > lg[e1]) e1 = e;
    float p1 = expf(lg[e1] - lg[e0]);
    float s  = 1.f + p1;
    int*   te = iws + 64;
    float* tw = (float*)(iws + 64 + NT*2);
    te[2*t]   = e0; te[2*t+1] = e1;
    tw[2*t]   = 1.f / s; tw[2*t+1] = p1 / s;
    atomicAdd(iws + e0, 1);
    atomicAdd(iws + e1, 1);
  }
}

// ---------------- scan ----------------
__global__ void moe_scan(int* iws) {
  if (threadIdx.x == 0 && blockIdx.x == 0) {
    int* cnt = iws; int* off = iws + 8; int* mbc = iws + 25;
    int o = 0, m = 0;
    for (int e = 0; e < NE; ++e) {
      off[e] = o; mbc[e] = m;
      o += cnt[e]; m += (cnt[e] + BM - 1) / BM;
    }
    off[NE] = o; mbc[NE] = m;
  }
}

// ---------------- fill slot lists ----------------
__global__ __launch_bounds__(256) void moe_fill(int* __restrict__ iws) {
  int t = blockIdx.x * 256 + threadIdx.x;
  const int*   te = iws + 64;
  const float* tw = (const float*)(iws + 64 + NT*2);
  int*   cursor   = iws + 17;
  const int* off  = iws + 8;
  int*   tok_slot = iws + 64 + NT*4;
  float* w_slot   = (float*)(iws + 64 + NT*6);
  #pragma unroll
  for (int k = 0; k < 2; ++k) {
    int e = te[2*t+k];
    int pos = atomicAdd(&cursor[e], 1);
    int s = off[e] + pos;
    tok_slot[s] = t;
    w_slot[s]   = tw[2*t+k];
  }
}

// ======== gemm1 v9: 4-phase counted-vmcnt schedule (R8 + race fix) ========
// 512 threads (8 waves 2M x 4N), tile 128 slots x 128 i-cols (dual G/U), BK=64.
// LDS 128 KiB: A 2-deep (staged 1 tile ahead), G/U 3-deep (2 ahead).
// Tile top: vmcnt(4) [drains this tile's {A,G,U}, leaves next tile's G/U in
// flight] -> s_barrier [R8 fix: makes every wave's writes visible before any
// wave's ds_read]. Then 4 phases: {ds_read subtile; issue stage loads;
// s_barrier; lgkmcnt(0)+sched_barrier; setprio(1); 8 MFMA; setprio(0);
// s_barrier}. LDS XOR: 16B slot' = slot ^ (row&7) on stage-SOURCE and ds_read
// (rule #21); addr = row*64 + slot*8 elems.
__global__ __launch_bounds__(512, 1) void moe_gemm1_f16(
    const _Float16* __restrict__ x16, const _Float16* __restrict__ gup16,
    const int* __restrict__ iws, _Float16* __restrict__ act)
{
  const int* cnt = iws; const int* off = iws + 8; const int* mbc = iws + 25;
  const int* tok_slot = iws + 64 + NT*4;
  int bid = blockIdx.x;
  int mb  = bid >> 5;            // 32 i-slices of 128 per mb, slice-minor
  int i0  = (bid & 31) << 7;
  if (mb >= mbc[NE]) return;
  int e = 0;
  while (mb >= mbc[e+1]) ++e;
  int mloc  = mb - mbc[e];
  int row0  = off[e] + mloc * BM;
  int nrows = cnt[e] - mloc * BM; if (nrows > BM) nrows = BM;

  __shared__ __align__(16) _Float16 Asb[2][128*64];  // 32 KB
  __shared__ __align__(16) _Float16 Gsb[3][128*64];  // 48 KB
  __shared__ __align__(16) _Float16 Usb[3][128*64];  // 48 KB  -> 128 KB

  int tid = threadIdx.x, wid = tid >> 6, lane = tid & 63;
  // staging: one issue-set = 512 lanes x 16B = 64 rows x 128B; wave w rows w*8..+8
  int srow = (wid << 3) + (lane >> 3);            // 0..63 within half
  int ss8  = ((lane & 7) ^ (srow & 7)) << 3;      // swizzled source col (elems)
  int r1   = srow + 64;                            // (r1&7)==(srow&7)
  int tokA0 = tok_slot[row0 + (srow < nrows ? srow : 0)];
  int tokA1 = tok_slot[row0 + (r1   < nrows ? r1   : 0)];
  const _Float16* pA0 = x16 + (size_t)tokA0 * NH + ss8;
  const _Float16* pA1 = x16 + (size_t)tokA1 * NH + ss8;
  const _Float16* pG0 = gup16 + ((size_t)e*2*NI + i0 + srow) * NH + ss8;
  const _Float16* pG1 = pG0 + (size_t)64 * NH;
  const _Float16* pU0 = pG0 + (size_t)NI * NH;
  const _Float16* pU1 = pG1 + (size_t)NI * NH;
  int ldst = wid << 9;                             // wave LDS chunk (elems)

  int wr = (wid >> 2) * 64, wc = (wid & 3) * 32;
  int fr = lane & 15, fq = lane >> 4;

  f32x4 accG[4][2] = {};
  f32x4 accU[4][2] = {};

  _Float16 *Aa = Asb[0], *Ab = Asb[1];
  _Float16 *G0b = Gsb[0], *G1b = Gsb[1], *G2b = Gsb[2];
  _Float16 *U0b = Usb[0], *U1b = Usb[1], *U2b = Usb[2];

#define SA0(B,kk) gload16(pA0 + (kk), (B) + ldst)
#define SA1(B,kk) gload16(pA1 + (kk), (B) + 4096 + ldst)
#define SG0(B,kk) gload16(pG0 + (kk), (B) + ldst)
#define SG1(B,kk) gload16(pG1 + (kk), (B) + 4096 + ldst)
#define SU0(B,kk) gload16(pU0 + (kk), (B) + ldst)
#define SU1(B,kk) gload16(pU1 + (kk), (B) + 4096 + ldst)
// ds_read of one 16B frag: row r, k-frag k; XOR slot with (r&7)
#define LDT(B,r,k) (*(const half8*)((B) + (size_t)(r)*64 + ((((k)*4+fq) ^ ((r)&7)) << 3)))

#define TILE1(Ac,Gc,Uc, S0,S1,S2,S3,S4,S5) do { \
  /* ---- P0: A(m01)+G reads | stage | 8 MFMA G-m01 ---- */ \
  half8 aa00=LDT(Ac,wr+fr,0),    aa01=LDT(Ac,wr+fr,1); \
  half8 aa10=LDT(Ac,wr+16+fr,0), aa11=LDT(Ac,wr+16+fr,1); \
  half8 g00=LDT(Gc,wc+fr,0),     g01=LDT(Gc,wc+fr,1); \
  half8 g10=LDT(Gc,wc+16+fr,0),  g11=LDT(Gc,wc+16+fr,1); \
  S0; \
  PIPE_BAR(); LGKM0(); \
  __builtin_amdgcn_s_setprio(1); \
  accG[0][0]=MF(aa00,g00,accG[0][0]); accG[0][0]=MF(aa01,g01,accG[0][0]); \
  accG[0][1]=MF(aa00,g10,accG[0][1]); accG[0][1]=MF(aa01,g11,accG[0][1]); \
  accG[1][0]=MF(aa10,g00,accG[1][0]); accG[1][0]=MF(aa11,g01,accG[1][0]); \
  accG[1][1]=MF(aa10,g10,accG[1][1]); accG[1][1]=MF(aa11,g11,accG[1][1]); \
  __builtin_amdgcn_s_setprio(0); \
  PIPE_BAR(); \
  /* ---- P1: U reads | stage | 8 MFMA U-m01 ---- */ \
  half8 u00=LDT(Uc,wc+fr,0),     u01=LDT(Uc,wc+fr,1); \
  half8 u10=LDT(Uc,wc+16+fr,0),  u11=LDT(Uc,wc+16+fr,1); \
  S1; S2; \
  PIPE_BAR(); LGKM0(); \
  __builtin_amdgcn_s_setprio(1); \
  accU[0][0]=MF(aa00,u00,accU[0][0]); accU[0][0]=MF(aa01,u01,accU[0][0]); \
  accU[0][1]=MF(aa00,u10,accU[0][1]); accU[0][1]=MF(aa01,u11,accU[0][1]); \
  accU[1][0]=MF(aa10,u00,accU[1][0]); accU[1][0]=MF(aa11,u01,accU[1][0]); \
  accU[1][1]=MF(aa10,u10,accU[1][1]); accU[1][1]=MF(aa11,u11,accU[1][1]); \
  __builtin_amdgcn_s_setprio(0); \
  PIPE_BAR(); \
  /* ---- P2: A(m23) reads | stage | 8 MFMA G-m23 ---- */ \
  half8 ab00=LDT(Ac,wr+32+fr,0), ab01=LDT(Ac,wr+32+fr,1); \
  half8 ab10=LDT(Ac,wr+48+fr,0), ab11=LDT(Ac,wr+48+fr,1); \
  S3; S4; \
  PIPE_BAR(); LGKM0(); \
  __builtin_amdgcn_s_setprio(1); \
  accG[2][0]=MF(ab00,g00,accG[2][0]); accG[2][0]=MF(ab01,g01,accG[2][0]); \
  accG[2][1]=MF(ab00,g10,accG[2][1]); accG[2][1]=MF(ab01,g11,accG[2][1]); \
  accG[3][0]=MF(ab10,g00,accG[3][0]); accG[3][0]=MF(ab11,g01,accG[3][0]); \
  accG[3][1]=MF(ab10,g10,accG[3][1]); accG[3][1]=MF(ab11,g11,accG[3][1]); \
  __builtin_amdgcn_s_setprio(0); \
  PIPE_BAR(); \
  /* ---- P3: stage | 8 MFMA U-m23 ---- */ \
  S5; \
  PIPE_BAR(); \
  __builtin_amdgcn_s_setprio(1); \
  accU[2][0]=MF(ab00,u00,accU[2][0]); accU[2][0]=MF(ab01,u01,accU[2][0]); \
  accU[2][1]=MF(ab00,u10,accU[2][1]); accU[2][1]=MF(ab01,u11,accU[2][1]); \
  accU[3][0]=MF(ab10,u00,accU[3][0]); accU[3][0]=MF(ab11,u01,accU[3][0]); \
  accU[3][1]=MF(ab10,u10,accU[3][1]); accU[3][1]=MF(ab11,u11,accU[3][1]); \
  __builtin_amdgcn_s_setprio(0); \
  PIPE_BAR(); \
} while (0)

#define ROT1() do { _Float16* t_; \
    t_ = Aa;  Aa  = Ab;  Ab  = t_; \
    t_ = G0b; G0b = G1b; G1b = G2b; G2b = t_; \
    t_ = U0b; U0b = U1b; U1b = U2b; U2b = t_; } while (0)

  // prologue: order must match steady-state (oldest: G0,U0,A0, then G1,U1)
  SG0(G0b, 0);  SG1(G0b, 0);  SU0(U0b, 0);  SU1(U0b, 0);
  SA0(Aa, 0);   SA1(Aa, 0);
  SG0(G1b, 64); SG1(G1b, 64); SU0(U1b, 64); SU1(U1b, 64);

  // NKT = NH/64 = 16 tiles. t=0..13 full stage; t=14 A-only; t=15 drain.
  for (int t = 0; t < 14; ++t) {
    PIPE_WAIT(4);
    PIPE_BAR();                       // R8 fix: publish writes before reads
    int kA = (t + 1) << 6, kG = (t + 2) << 6;
    TILE1(Aa, G0b, U0b,
          SA0(Ab, kA), SA1(Ab, kA),
          SG0(G2b, kG), SG1(G2b, kG),
          SU0(U2b, kG), SU1(U2b, kG));
    ROT1();
  }
  {
    PIPE_WAIT(4);
    PIPE_BAR();                       // R8 fix
    int kA = 15 << 6;
    TILE1(Aa, G0b, U0b,
          SA0(Ab, kA), SA1(Ab, kA),
          (void)0, (void)0, (void)0, (void)0);
    ROT1();
  }
  PIPE_WAIT(0);
  PIPE_BAR();                         // R8 fix
  TILE1(Aa, G0b, U0b, (void)0, (void)0, (void)0, (void)0, (void)0, (void)0);

#undef TILE1
#undef ROT1
#undef SA0
#undef SA1
#undef SG0
#undef SG1
#undef SU0
#undef SU1
#undef LDT

  // epilogue: act[slot][i0 + col] = silu(g)*u
  #pragma unroll
  for (int m = 0; m < 4; ++m) {
    #pragma unroll
    for (int j = 0; j < 4; ++j) {
      int rl = wr + m*16 + fq*4 + j;
      if (rl < nrows) {
        _Float16* dst = act + (size_t)(row0 + rl) * NI + i0 + wc + fr;
        #pragma unroll
        for (int n = 0; n < 2; ++n) {
          float g = accG[m][n][j], u = accU[m][n][j];
          float a = (g / (1.f + __expf(-g))) * u;
          dst[n*16] = (_Float16)a;
        }
      }
    }
  }
}

// ======== gemm2 (unchanged R7): 3-stage counted-vmcnt, 256 thr, BK=32 ========
__global__ __launch_bounds__(256, 4) void moe_gemm2_f16(
    const _Float16* __restrict__ act, const _Float16* __restrict__ dp16,
    const int* __restrict__ iws, float* __restrict__ out)
{
  const int* cnt = iws; const int* off = iws + 8; const int* mbc = iws + 25;
  const int* tok_slot = iws + 64 + NT*4;
  const float* w_slot = (const float*)(iws + 64 + NT*6);
  int bid = blockIdx.x;
  int mb  = bid >> 4;            // 16 h-slices per mb, slice-minor
  int h0  = (bid & 15) << 6;
  if (mb >= mbc[NE]) return;
  int e = 0;
  while (mb >= mbc[e+1]) ++e;
  int mloc  = mb - mbc[e];
  int row0  = off[e] + mloc * BM;
  int nrows = cnt[e] - mloc * BM; if (nrows > BM) nrows = BM;

  __shared__ __align__(16) _Float16 Al[3][BM * BK];   // 8 KB / stage
  __shared__ __align__(16) _Float16 Bl[3][64 * BK];   // 4 KB / stage -> 36 KB

  int tid = threadIdx.x, wid = tid >> 6, lane = tid & 63;
  int sr0 = wid*16 + (lane >> 2);
  int sr1 = 64 + sr0;
  int slot = lane & 3;
  int ks0 = (slot ^ ((sr0 >> 1) & 3)) * 8;
  int ks1 = (slot ^ ((sr1 >> 1) & 3)) * 8;

  const _Float16* pA0 = act + (size_t)(row0 + (sr0 < nrows ? sr0 : 0)) * NI + ks0;
  const _Float16* pA1 = act + (size_t)(row0 + (sr1 < nrows ? sr1 : 0)) * NI + ks1;
  const _Float16* pB  = dp16 + ((size_t)e*NH + h0 + sr0) * NI + ks0;

  int wr = (wid >> 1) * 64, wc = (wid & 1) * 32;
  int fr = lane & 15, fq = lane >> 4;

  f32x4 acc[4][2] = {};

  _Float16 *A0 = &Al[0][0], *A1 = &Al[1][0], *A2 = &Al[2][0];
  _Float16 *B0 = &Bl[0][0], *B1 = &Bl[1][0], *B2 = &Bl[2][0];

#define STAGE2(Ab, Bb, kk) do { \
    gload16(pA0 + (kk), (Ab) + wid*512); \
    gload16(pA1 + (kk), (Ab) + (4+wid)*512); \
    gload16(pB  + (kk), (Bb) + wid*512); \
  } while (0)

#define COMPUTE2(Ab, Bb) do { \
    half8 aF[4]; \
    _Pragma("unroll") \
    for (int m = 0; m < 4; ++m) { \
      int r = wr + m*16 + fr; \
      aF[m] = *(const half8*)((Ab) + r*BK + ((fq ^ ((r>>1)&3)) * 8)); \
    } \
    __builtin_amdgcn_s_setprio(1); \
    _Pragma("unroll") \
    for (int n = 0; n < 2; ++n) { \
      int rb = wc + n*16 + fr; \
      half8 b = *(const half8*)((Bb) + rb*BK + ((fq ^ ((rb>>1)&3)) * 8)); \
      _Pragma("unroll") \
      for (int m = 0; m < 4; ++m) \
        acc[m][n] = __builtin_amdgcn_mfma_f32_16x16x32_f16(aF[m], b, acc[m][n], 0, 0, 0); \
    } \
    __builtin_amdgcn_s_setprio(0); \
  } while (0)

#define ROT2() do { _Float16* t_; \
    t_ = A0; A0 = A1; A1 = A2; A2 = t_; \
    t_ = B0; B0 = B1; B1 = B2; B2 = t_; } while (0)

  STAGE2(A0, B0, 0);
  STAGE2(A1, B1, BK);

  for (int k0 = 0; k0 + 2*BK < NI; k0 += BK) {
    PIPE_WAIT(3);
    PIPE_BAR();
    STAGE2(A2, B2, k0 + 2*BK);
    COMPUTE2(A0, B0);
    ROT2();
  }
  PIPE_WAIT(3);
  PIPE_BAR();
  COMPUTE2(A0, B0);
  ROT2();
  PIPE_WAIT(0);
  PIPE_BAR();
  COMPUTE2(A0, B0);

#undef STAGE2
#undef COMPUTE2
#undef ROT2

  #pragma unroll
  for (int m = 0; m < 4; ++m) {
    #pragma unroll
    for (int j = 0; j < 4; ++j) {
      int rl = wr + m*16 + fq*4 + j;
      if (rl < nrows) {
        int slotr = row0 + rl;
        float wgt = w_slot[slotr];
        int tok   = tok_slot[slotr];
        float* dst = out + (size_t)tok * NH + h0 + wc + fr;
        #pragma unroll
        for (int n = 0; n < 2; ++n)
          atomicAdd(dst + n*16, acc[m][n][j] * wgt);
      }
    }
  }
}

extern "C" void kernel_launch(void* const* d_in, const int* in_sizes, int n_in,
                              void* d_out, int out_size, void* d_ws, size_t ws_size,
                              hipStream_t stream) {
  const float* x   = (const float*)d_in[0];
  const float* rw  = (const float*)d_in[1];
  const float* gup = (const float*)d_in[2];
  const float* dp  = (const float*)d_in[3];
  float* out = (float*)d_out;
  int* iws = (int*)d_ws;
  _Float16* x16   = (_Float16*)((char*)d_ws + OFF_X16);
  _Float16* act   = (_Float16*)((char*)d_ws + OFF_ACT);
  _Float16* gup16 = (_Float16*)((char*)d_ws + OFF_GUP16);
  _Float16* dp16  = (_Float16*)((char*)d_ws + OFF_DP16);

  hipMemsetAsync(d_out, 0, (size_t)NT * NH * sizeof(float), stream);
  hipMemsetAsync(d_ws, 0, 512, stream);

  convert_w<<<2048, 256, 0, stream>>>(gup, gup16, NE*2*NI*NH/8);
  convert_w<<<2048, 256, 0, stream>>>(dp,  dp16,  NE*NH*NI/8);

  moe_router<<<NT / 4, 256, 0, stream>>>(x, rw, iws, x16);
  moe_scan<<<1, 64, 0, stream>>>(iws);
  moe_fill<<<NT / 256, 256, 0, stream>>>(iws);

  // 1D identity grids (slice-minor): B L2-stationary per XCD (R7 win)
  int nmb = NT * 2 / BM + NE;                                 // 136
  moe_gemm1_f16<<<nmb * (NI / 128), 512, 0, stream>>>(x16, gup16, iws, act); // 4352
  moe_gemm2_f16<<<nmb * (NH / 64), 256, 0, stream>>>(act, dp16, iws, out);   // 2176
}

// Round 10
// 984.082 us; speedup vs baseline: 1.1061x; 1.1061x over previous
//
#include <hip/hip_runtime.h>
#include <stdint.h>
#include <math.h>

#define NE 8
#define NT 8192
#define NH 1024
#define NI 4096
#define BM 128
#define BK 32

typedef _Float16 half8 __attribute__((ext_vector_type(8)));
typedef float f32x4 __attribute__((ext_vector_type(4)));

// ---------------- workspace layout ----------------
// ints at base: [0..8) cnt  [8..17) off  [17..25) cursor  [25..34) mbcum
// int 64..            : te[NT*2]
// int 64+NT*2         : tw[NT*2] (float)
// int 64+NT*4         : tok_slot[NT*2]
// int 64+NT*6         : w_slot[NT*2] (float)
// byte 0.5MiB : x16   (NT*NH f16, 16 MiB)
// byte 18MiB  : act   (NT*2*NI f16, 128 MiB)
// byte 146MiB : gup16 (E*2*NI*NH f16, 128 MiB)
// byte 274MiB : dp16  (E*NH*NI f16, 64 MiB)   -> ends 338 MiB (fits, proven R2-R9)
#define OFF_X16   (512u << 10)
#define OFF_ACT   (18u << 20)
#define OFF_GUP16 (146ull << 20)
#define OFF_DP16  (274ull << 20)

__device__ __forceinline__ half8 pack_half8(float4 a, float4 b) {
  half8 h;
  h[0] = (_Float16)a.x; h[1] = (_Float16)a.y; h[2] = (_Float16)a.z; h[3] = (_Float16)a.w;
  h[4] = (_Float16)b.x; h[5] = (_Float16)b.y; h[6] = (_Float16)b.z; h[7] = (_Float16)b.w;
  return h;
}

__device__ __forceinline__ void gload16(const void* g, void* l) {
  __builtin_amdgcn_global_load_lds(
      (const __attribute__((address_space(1))) uint32_t*)g,
      (__attribute__((address_space(3))) uint32_t*)l, 16, 0, 0);
}

// counted-vmcnt pipeline primitives (T4): raw barrier, NO compiler drain.
// RULE (R8): every tile-top PIPE_WAIT must be followed by PIPE_BAR before any
// ds_read of staged data (vmcnt is per-wave; the barrier publishes the writes).
#define PIPE_WAIT(N) asm volatile("s_waitcnt vmcnt(" #N ")" ::: "memory")
#define PIPE_BAR() do { asm volatile("" ::: "memory"); \
                        __builtin_amdgcn_s_barrier(); \
                        asm volatile("" ::: "memory"); } while (0)

// ---------------- weight convert f32 -> f16 ----------------
__global__ __launch_bounds__(256) void convert_w(
    const float* __restrict__ src, _Float16* __restrict__ dst, int n8)
{
  int stride = gridDim.x * 256;
  for (int i = blockIdx.x * 256 + threadIdx.x; i < n8; i += stride) {
    const float4* p = (const float4*)(src + (size_t)i * 8);
    float4 a = p[0], b = p[1];
    *(half8*)(dst + (size_t)i * 8) = pack_half8(a, b);
  }
}

// ---------------- router ----------------
__global__ __launch_bounds__(256) void moe_router(
    const float* __restrict__ x, const float* __restrict__ rw,
    int* __restrict__ iws, _Float16* __restrict__ x16)
{
  int wid  = threadIdx.x >> 6;
  int lane = threadIdx.x & 63;
  int t = (blockIdx.x << 2) + wid;  // one wave per token

  const float4* xp4 = (const float4*)(x + (size_t)t * NH + lane * 16);
  float xv[16];
  #pragma unroll
  for (int j = 0; j < 4; ++j) {
    float4 v = xp4[j];
    xv[4*j+0] = v.x; xv[4*j+1] = v.y; xv[4*j+2] = v.z; xv[4*j+3] = v.w;
  }
  half8 h0, h1;
  #pragma unroll
  for (int j = 0; j < 8; ++j) { h0[j] = (_Float16)xv[j]; h1[j] = (_Float16)xv[8+j]; }
  half8* xo = (half8*)(x16 + (size_t)t * NH + lane * 16);
  xo[0] = h0; xo[1] = h1;

  float lg[NE];
  #pragma unroll
  for (int e = 0; e < NE; ++e) {
    const float4* wp4 = (const float4*)(rw + e * NH + lane * 16);
    float s = 0.f;
    #pragma unroll
    for (int j = 0; j < 4; ++j) {
      float4 w = wp4[j];
      s += xv[4*j+0]*w.x + xv[4*j+1]*w.y + xv[4*j+2]*w.z + xv[4*j+3]*w.w;
    }
    lg[e] = s;
  }
  #pragma unroll
  for (int d = 32; d > 0; d >>= 1) {
    #pragma unroll
    for (int e = 0; e < NE; ++e) lg[e] += __shfl_xor(lg[e], d, 64);
  }
  if (lane == 0) {
    int e0 = 0;
    #pragma unroll
    for (int e = 1; e < NE; ++e) if (lg[e] > lg[e0]) e0 = e;
    int e1 = (e0 == 0) ? 1 : 0;
    #pragma unroll
    for (int e = 0; e < NE; ++e) if (e != e0 && lg[e] > lg[e1]) e1 = e;
    float p1 = expf(lg[e1] - lg[e0]);
    float s  = 1.f + p1;
    int*   te = iws + 64;
    float* tw = (float*)(iws + 64 + NT*2);
    te[2*t]   = e0; te[2*t+1] = e1;
    tw[2*t]   = 1.f / s; tw[2*t+1] = p1 / s;
    atomicAdd(iws + e0, 1);
    atomicAdd(iws + e1, 1);
  }
}

// ---------------- scan ----------------
__global__ void moe_scan(int* iws) {
  if (threadIdx.x == 0 && blockIdx.x == 0) {
    int* cnt = iws; int* off = iws + 8; int* mbc = iws + 25;
    int o = 0, m = 0;
    for (int e = 0; e < NE; ++e) {
      off[e] = o; mbc[e] = m;
      o += cnt[e]; m += (cnt[e] + BM - 1) / BM;
    }
    off[NE] = o; mbc[NE] = m;
  }
}

// ---------------- fill slot lists ----------------
__global__ __launch_bounds__(256) void moe_fill(int* __restrict__ iws) {
  int t = blockIdx.x * 256 + threadIdx.x;
  const int*   te = iws + 64;
  const float* tw = (const float*)(iws + 64 + NT*2);
  int*   cursor   = iws + 17;
  const int* off  = iws + 8;
  int*   tok_slot = iws + 64 + NT*4;
  float* w_slot   = (float*)(iws + 64 + NT*6);
  #pragma unroll
  for (int k = 0; k < 2; ++k) {
    int e = te[2*t+k];
    int pos = atomicAdd(&cursor[e], 1);
    int s = off[e] + pos;
    tok_slot[s] = t;
    w_slot[s]   = tw[2*t+k];
  }
}

// ======== GEMMs: 3-stage counted-vmcnt (R7 champion shape, both kernels) ======
// Identity grid order (mb-major, slice-minor): round-robin bid%8->XCD keeps each
// XCD's B-row subset L2-stationary across all mbs of an expert (R7: FETCH 1.09GB
// -> 0.38GB). Per iter: vmcnt(4)->s_barrier->stage(t+2)->compute(t). XOR swizzle
// (16B slot ^ (row>>1)&3) on global SOURCE + ds_read side (rule #21).

// gemm1: block = 128 slots x 64 i-cols, dual gate/up; 4 loads + 16 MFMA / step.
__global__ __launch_bounds__(256, 2) void moe_gemm1_f16(
    const _Float16* __restrict__ x16, const _Float16* __restrict__ gup16,
    const int* __restrict__ iws, _Float16* __restrict__ act)
{
  const int* cnt = iws; const int* off = iws + 8; const int* mbc = iws + 25;
  const int* tok_slot = iws + 64 + NT*4;
  int bid = blockIdx.x;
  int mb  = bid >> 6;            // 64 i-slices per mb, slice-minor
  int i0  = (bid & 63) << 6;
  if (mb >= mbc[NE]) return;
  int e = 0;
  while (mb >= mbc[e+1]) ++e;
  int mloc  = mb - mbc[e];
  int row0  = off[e] + mloc * BM;
  int nrows = cnt[e] - mloc * BM; if (nrows > BM) nrows = BM;

  __shared__ __align__(16) _Float16 Al [3][BM * BK];   // 8 KB / stage
  __shared__ __align__(16) _Float16 Bgl[3][64 * BK];   // 4 KB / stage
  __shared__ __align__(16) _Float16 Bul[3][64 * BK];   // total 48 KB

  int tid = threadIdx.x, wid = tid >> 6, lane = tid & 63;
  int sr0 = wid*16 + (lane >> 2);
  int sr1 = 64 + sr0;
  int slot = lane & 3;
  int ks0 = (slot ^ ((sr0 >> 1) & 3)) * 8;
  int ks1 = (slot ^ ((sr1 >> 1) & 3)) * 8;

  int tok0 = tok_slot[row0 + (sr0 < nrows ? sr0 : 0)];
  int tok1 = tok_slot[row0 + (sr1 < nrows ? sr1 : 0)];
  const _Float16* pA0 = x16 + (size_t)tok0 * NH + ks0;
  const _Float16* pA1 = x16 + (size_t)tok1 * NH + ks1;
  const _Float16* pBg = gup16 + ((size_t)e*2*NI + i0 + sr0) * NH + ks0;
  const _Float16* pBu = pBg + (size_t)NI * NH;

  int wr = (wid >> 1) * 64, wc = (wid & 1) * 32;
  int fr = lane & 15, fq = lane >> 4;

  f32x4 accG[4][2] = {};
  f32x4 accU[4][2] = {};

  _Float16 *A0 = &Al[0][0], *A1 = &Al[1][0], *A2 = &Al[2][0];
  _Float16 *G0 = &Bgl[0][0], *G1 = &Bgl[1][0], *G2 = &Bgl[2][0];
  _Float16 *U0 = &Bul[0][0], *U1 = &Bul[1][0], *U2 = &Bul[2][0];

#define STAGE1(Ab, Gb, Ub, kk) do { \
    gload16(pA0 + (kk), (Ab) + wid*512); \
    gload16(pA1 + (kk), (Ab) + (4+wid)*512); \
    gload16(pBg + (kk), (Gb) + wid*512); \
    gload16(pBu + (kk), (Ub) + wid*512); \
  } while (0)

#define COMPUTE1(Ab, Gb, Ub) do { \
    half8 aF[4]; \
    _Pragma("unroll") \
    for (int m = 0; m < 4; ++m) { \
      int r = wr + m*16 + fr; \
      aF[m] = *(const half8*)((Ab) + r*BK + ((fq ^ ((r>>1)&3)) * 8)); \
    } \
    __builtin_amdgcn_s_setprio(1); \
    _Pragma("unroll") \
    for (int n = 0; n < 2; ++n) { \
      int rb = wc + n*16 + fr; \
      int bo = rb*BK + ((fq ^ ((rb>>1)&3)) * 8); \
      half8 bg = *(const half8*)((Gb) + bo); \
      half8 bu = *(const half8*)((Ub) + bo); \
      _Pragma("unroll") \
      for (int m = 0; m < 4; ++m) \
        accG[m][n] = __builtin_amdgcn_mfma_f32_16x16x32_f16(aF[m], bg, accG[m][n], 0, 0, 0); \
      _Pragma("unroll") \
      for (int m = 0; m < 4; ++m) \
        accU[m][n] = __builtin_amdgcn_mfma_f32_16x16x32_f16(aF[m], bu, accU[m][n], 0, 0, 0); \
    } \
    __builtin_amdgcn_s_setprio(0); \
  } while (0)

#define ROT1() do { _Float16* t_; \
    t_ = A0; A0 = A1; A1 = A2; A2 = t_; \
    t_ = G0; G0 = G1; G1 = G2; G2 = t_; \
    t_ = U0; U0 = U1; U1 = U2; U2 = t_; } while (0)

  STAGE1(A0, G0, U0, 0);
  STAGE1(A1, G1, U1, BK);

  for (int k0 = 0; k0 + 2*BK < NH; k0 += BK) {
    PIPE_WAIT(4);
    PIPE_BAR();
    STAGE1(A2, G2, U2, k0 + 2*BK);
    COMPUTE1(A0, G0, U0);
    ROT1();
  }
  PIPE_WAIT(4);
  PIPE_BAR();
  COMPUTE1(A0, G0, U0);
  ROT1();
  PIPE_WAIT(0);
  PIPE_BAR();
  COMPUTE1(A0, G0, U0);

#undef STAGE1
#undef COMPUTE1
#undef ROT1

  #pragma unroll
  for (int m = 0; m < 4; ++m) {
    #pragma unroll
    for (int j = 0; j < 4; ++j) {
      int rl = wr + m*16 + fq*4 + j;
      if (rl < nrows) {
        _Float16* dst = act + (size_t)(row0 + rl) * NI + i0 + wc + fr;
        #pragma unroll
        for (int n = 0; n < 2; ++n) {
          float g = accG[m][n][j], u = accU[m][n][j];
          float a = (g / (1.f + __expf(-g))) * u;
          dst[n*16] = (_Float16)a;
        }
      }
    }
  }
}

// gemm2 v10: block = 128 slots x 128 h-cols (R7-champion shape: 4 loads +
// 16 MFMA / K-step), acc[4][4]=64 regs, K=4096 -> long pipeline. grid 136x8.
__global__ __launch_bounds__(256, 2) void moe_gemm2_f16(
    const _Float16* __restrict__ act, const _Float16* __restrict__ dp16,
    const int* __restrict__ iws, float* __restrict__ out)
{
  const int* cnt = iws; const int* off = iws + 8; const int* mbc = iws + 25;
  const int* tok_slot = iws + 64 + NT*4;
  const float* w_slot = (const float*)(iws + 64 + NT*6);
  int bid = blockIdx.x;
  int mb  = bid >> 3;            // 8 h-slices of 128 per mb, slice-minor
  int h0  = (bid & 7) << 7;
  if (mb >= mbc[NE]) return;
  int e = 0;
  while (mb >= mbc[e+1]) ++e;
  int mloc  = mb - mbc[e];
  int row0  = off[e] + mloc * BM;
  int nrows = cnt[e] - mloc * BM; if (nrows > BM) nrows = BM;

  __shared__ __align__(16) _Float16 Al[3][BM  * BK];   // 8 KB / stage
  __shared__ __align__(16) _Float16 Bl[3][128 * BK];   // 8 KB / stage -> 48 KB

  int tid = threadIdx.x, wid = tid >> 6, lane = tid & 63;
  int sr0 = wid*16 + (lane >> 2);
  int sr1 = 64 + sr0;
  int slot = lane & 3;
  int ks0 = (slot ^ ((sr0 >> 1) & 3)) * 8;
  int ks1 = (slot ^ ((sr1 >> 1) & 3)) * 8;

  const _Float16* pA0 = act + (size_t)(row0 + (sr0 < nrows ? sr0 : 0)) * NI + ks0;
  const _Float16* pA1 = act + (size_t)(row0 + (sr1 < nrows ? sr1 : 0)) * NI + ks1;
  const _Float16* pB0 = dp16 + ((size_t)e*NH + h0 + sr0) * NI + ks0;
  const _Float16* pB1 = dp16 + ((size_t)e*NH + h0 + sr1) * NI + ks1;

  int wr = (wid >> 1) * 64, wc = (wid & 1) * 64;
  int fr = lane & 15, fq = lane >> 4;

  f32x4 acc[4][4] = {};

  _Float16 *A0 = &Al[0][0], *A1 = &Al[1][0], *A2 = &Al[2][0];
  _Float16 *B0 = &Bl[0][0], *B1 = &Bl[1][0], *B2 = &Bl[2][0];

#define STAGE2(Ab, Bb, kk) do { \
    gload16(pA0 + (kk), (Ab) + wid*512); \
    gload16(pA1 + (kk), (Ab) + (4+wid)*512); \
    gload16(pB0 + (kk), (Bb) + wid*512); \
    gload16(pB1 + (kk), (Bb) + (4+wid)*512); \
  } while (0)

#define COMPUTE2(Ab, Bb) do { \
    half8 aF[4]; \
    _Pragma("unroll") \
    for (int m = 0; m < 4; ++m) { \
      int r = wr + m*16 + fr; \
      aF[m] = *(const half8*)((Ab) + r*BK + ((fq ^ ((r>>1)&3)) * 8)); \
    } \
    __builtin_amdgcn_s_setprio(1); \
    _Pragma("unroll") \
    for (int n = 0; n < 4; ++n) { \
      int rb = wc + n*16 + fr; \
      half8 b = *(const half8*)((Bb) + rb*BK + ((fq ^ ((rb>>1)&3)) * 8)); \
      _Pragma("unroll") \
      for (int m = 0; m < 4; ++m) \
        acc[m][n] = __builtin_amdgcn_mfma_f32_16x16x32_f16(aF[m], b, acc[m][n], 0, 0, 0); \
    } \
    __builtin_amdgcn_s_setprio(0); \
  } while (0)

#define ROT2() do { _Float16* t_; \
    t_ = A0; A0 = A1; A1 = A2; A2 = t_; \
    t_ = B0; B0 = B1; B1 = B2; B2 = t_; } while (0)

  STAGE2(A0, B0, 0);
  STAGE2(A1, B1, BK);

  for (int k0 = 0; k0 + 2*BK < NI; k0 += BK) {
    PIPE_WAIT(4);
    PIPE_BAR();
    STAGE2(A2, B2, k0 + 2*BK);
    COMPUTE2(A0, B0);
    ROT2();
  }
  PIPE_WAIT(4);
  PIPE_BAR();
  COMPUTE2(A0, B0);
  ROT2();
  PIPE_WAIT(0);
  PIPE_BAR();
  COMPUTE2(A0, B0);

#undef STAGE2
#undef COMPUTE2
#undef ROT2

  #pragma unroll
  for (int m = 0; m < 4; ++m) {
    #pragma unroll
    for (int j = 0; j < 4; ++j) {
      int rl = wr + m*16 + fq*4 + j;
      if (rl < nrows) {
        int slotr = row0 + rl;
        float wgt = w_slot[slotr];
        int tok   = tok_slot[slotr];
        float* dst = out + (size_t)tok * NH + h0 + wc + fr;
        #pragma unroll
        for (int n = 0; n < 4; ++n)
          atomicAdd(dst + n*16, acc[m][n][j] * wgt);
      }
    }
  }
}

extern "C" void kernel_launch(void* const* d_in, const int* in_sizes, int n_in,
                              void* d_out, int out_size, void* d_ws, size_t ws_size,
                              hipStream_t stream) {
  const float* x   = (const float*)d_in[0];
  const float* rw  = (const float*)d_in[1];
  const float* gup = (const float*)d_in[2];
  const float* dp  = (const float*)d_in[3];
  float* out = (float*)d_out;
  int* iws = (int*)d_ws;
  _Float16* x16   = (_Float16*)((char*)d_ws + OFF_X16);
  _Float16* act   = (_Float16*)((char*)d_ws + OFF_ACT);
  _Float16* gup16 = (_Float16*)((char*)d_ws + OFF_GUP16);
  _Float16* dp16  = (_Float16*)((char*)d_ws + OFF_DP16);

  hipMemsetAsync(d_out, 0, (size_t)NT * NH * sizeof(float), stream);
  hipMemsetAsync(d_ws, 0, 512, stream);

  convert_w<<<4096, 256, 0, stream>>>(gup, gup16, NE*2*NI*NH/8);
  convert_w<<<4096, 256, 0, stream>>>(dp,  dp16,  NE*NH*NI/8);

  moe_router<<<NT / 4, 256, 0, stream>>>(x, rw, iws, x16);
  moe_scan<<<1, 64, 0, stream>>>(iws);
  moe_fill<<<NT / 256, 256, 0, stream>>>(iws);

  // 1D identity grids (slice-minor): B L2-stationary per XCD (R7 win)
  int nmb = NT * 2 / BM + NE;                                  // 136
  moe_gemm1_f16<<<nmb * (NI / 64), 256, 0, stream>>>(x16, gup16, iws, act);  // 8704
  moe_gemm2_f16<<<nmb * (NH / 128), 256, 0, stream>>>(act, dp16, iws, out);  // 1088
}